// Round 8
// baseline (546.250 us; speedup 1.0000x reference)
//
#include <hip/hip_runtime.h>
#include <hip/hip_bf16.h>

typedef __hip_bfloat16 bf16;

// Problem constants
constexpr int Nn  = 4;
constexpr int Ci  = 256;
constexpr int Cc  = 64;
constexpr int Hh  = 128;
constexpr int Ww  = 128;
constexpr int HWh = Hh * Ww;
constexpr int Hl  = 64;
constexpr int Wl  = 64;
constexpr int HWl = Hl * Wl;
constexpr int K2L = 25;
constexpr int K2H = 9;

// Output element offsets (in output elements): [mask | hr_out | lr_out]
constexpr size_t OFF_MASK = 0;
constexpr size_t OFF_HR   = (size_t)Nn * K2L * HWh;            // 1,638,400
constexpr size_t OFF_LR   = OFF_HR + (size_t)Nn * Ci * HWh;    // 18,415,616

// Arena A (inside out_lr region; min capacity 8,388,608 f32 in bf16 mode)
constexpr size_t A_CHF    = 0;        // 4,194,304  [D2-D5]
constexpr size_t A_MLRHR  = 0;        // 1,638,400  [D6-D7]  (chf dead)
constexpr size_t A_MLRLL  = 4300000;  //   409,600  [D4-D7]
constexpr size_t A_CLFE2  = 4800000;  //   147,456  [D4-D8]
constexpr size_t A_MHRRAW = 5000000;  //   589,824  [D8-D9] raw mask_hr
constexpr size_t A_WHR    = 7800000;  // 16,384 weights, live D1-D6
constexpr size_t A_WLR    = 7820000;  // 16,384
constexpr size_t A_WENC   = 7840000;  // 14,400
constexpr size_t A_WENC2  = 7860000;  //  5,184
constexpr size_t A_BHR    = 7870000;  // 64
constexpr size_t A_BLR    = 7870100;  // 64
constexpr size_t A_BENC   = 7870200;  // 64
constexpr size_t A_BENC2  = 7870300;  // 64   -> top 7,870,364 < 8,388,608 OK

// Arena B (inside out_hr region)
constexpr size_t B_CLF    = 0;        // 1,048,576  [D2-D4]
constexpr size_t B_CHF2   = 1100000;  // 4,194,304  [D5-D6]
constexpr size_t B_MHRHR  = 5300000;  //   589,824  [D3-D8]  -> top 5,889,824 OK
constexpr size_t B_MLR    = 0;        // 1,638,400  [D7-D8]

__device__ __forceinline__ float tofloat(float v) { return v; }
__device__ __forceinline__ float tofloat(bf16 v) { return __bfloat162float(v); }

template<typename T> __device__ __forceinline__ T fromfloat(float v);
template<> __device__ __forceinline__ float fromfloat<float>(float v) { return v; }
template<> __device__ __forceinline__ bf16  fromfloat<bf16>(float v)  { return __float2bfloat16(v); }

__device__ __forceinline__ unsigned short bfbits(bf16 v) {
  return *reinterpret_cast<unsigned short*>(&v);
}

// f32 scratch pointer inside an output region whose byte address depends on
// the detected output dtype (region offsets are in OUTPUT elements).
__device__ __forceinline__ float* scrp(void* d, int f32, size_t reg, size_t off) {
  float* b = f32 ? ((float*)d + reg) : (float*)((bf16*)d + reg);
  return b + off;
}

// ---------------------------------------------------------------------------
// dtype detector
// ---------------------------------------------------------------------------
__global__ void detect_dtype(const void* feat, int* flag) {
  __shared__ int s;
  if (threadIdx.x == 0) s = 0;
  __syncthreads();
  unsigned short b = ((const unsigned short*)feat)[threadIdx.x];
  float v = __uint_as_float(((unsigned int)b) << 16);
  if (!(fabsf(v) < 1000.0f)) atomicOr(&s, 1);
  __syncthreads();
  if (threadIdx.x == 0) *flag = s;
}

// ---------------------------------------------------------------------------
// Weight prep (dtype-dual)
// ---------------------------------------------------------------------------
template<typename T>
__device__ void prep_body(const T* hw, const T* hb, const T* lw, const T* lb,
                          const T* ew, const T* eb, const T* e2w, const T* e2b,
                          float* whr, float* wlr, float* wenc, float* wenc2,
                          float* bhr, float* blr, float* benc, float* benc2) {
  int tid = blockIdx.x * 256 + threadIdx.x, nt = gridDim.x * 256;
  for (int i = tid; i < Cc * Ci; i += nt) {
    int co = i / Ci, ci = i % Ci;
    whr[ci * Cc + co] = tofloat(hw[i]);
    wlr[ci * Cc + co] = tofloat(lw[i]);
  }
  for (int i = tid; i < K2L * Cc * 9; i += nt) {
    int ko = i / (Cc * 9), r = i % (Cc * 9), ci = r / 9, k = r % 9;
    wenc[(ci * K2L + ko) * 9 + k] = tofloat(ew[i]);
  }
  for (int i = tid; i < K2H * Cc * 9; i += nt) {
    int ko = i / (Cc * 9), r = i % (Cc * 9), ci = r / 9, k = r % 9;
    wenc2[(ci * K2H + ko) * 9 + k] = tofloat(e2w[i]);
  }
  if (tid < Cc)  { bhr[tid] = tofloat(hb[tid]); blr[tid] = tofloat(lb[tid]); }
  if (tid < K2L) benc[tid]  = tofloat(eb[tid]);
  if (tid < K2H) benc2[tid] = tofloat(e2b[tid]);
}

__global__ void prep_weights(const int* flag, void* dout,
                             const void* hw, const void* hb, const void* lw, const void* lb,
                             const void* ew, const void* eb, const void* e2w, const void* e2b) {
  int f32 = *flag;
  float* whr   = scrp(dout, f32, OFF_LR, A_WHR);
  float* wlr   = scrp(dout, f32, OFF_LR, A_WLR);
  float* wenc  = scrp(dout, f32, OFF_LR, A_WENC);
  float* wenc2 = scrp(dout, f32, OFF_LR, A_WENC2);
  float* bhr   = scrp(dout, f32, OFF_LR, A_BHR);
  float* blr   = scrp(dout, f32, OFF_LR, A_BLR);
  float* benc  = scrp(dout, f32, OFF_LR, A_BENC);
  float* benc2 = scrp(dout, f32, OFF_LR, A_BENC2);
  if (f32) prep_body<float>((const float*)hw, (const float*)hb, (const float*)lw, (const float*)lb,
                            (const float*)ew, (const float*)eb, (const float*)e2w, (const float*)e2b,
                            whr, wlr, wenc, wenc2, bhr, blr, benc, benc2);
  else     prep_body<bf16>((const bf16*)hw, (const bf16*)hb, (const bf16*)lw, (const bf16*)lb,
                           (const bf16*)ew, (const bf16*)eb, (const bf16*)e2w, (const bf16*)e2b,
                           whr, wlr, wenc, wenc2, bhr, blr, benc, benc2);
}

// ---------------------------------------------------------------------------
// 1x1 conv: 2 ADJACENT pixels/thread, packed loads (bf16x2 / f32x2), unroll 8.
// ---------------------------------------------------------------------------
template<typename T, int CW>
__device__ __forceinline__ void conv1x1_core(const T* __restrict__ in, const float* __restrict__ wt,
                                             const float* __restrict__ bias, float* __restrict__ out,
                                             int P, int n, int pbase, int co0) {
  const T* inp = in + (size_t)n * Ci * P + pbase;
  float acc0[CW], acc1[CW];
  #pragma unroll
  for (int c = 0; c < CW; ++c) { float b = bias[co0 + c]; acc0[c] = b; acc1[c] = b; }

  #pragma unroll 8
  for (int ci = 0; ci < Ci; ++ci) {
    float v0, v1;
    if (sizeof(T) == 2) {
      unsigned u = *reinterpret_cast<const unsigned*>(inp + (size_t)ci * P);
      v0 = __uint_as_float(u << 16);
      v1 = __uint_as_float(u & 0xffff0000u);
    } else {
      float2 f = *reinterpret_cast<const float2*>(inp + (size_t)ci * P);
      v0 = f.x; v1 = f.y;
    }
    const float* wr = wt + ci * Cc + co0;
    #pragma unroll
    for (int c = 0; c < CW; ++c) {
      float wv = wr[c];
      acc0[c] = fmaf(v0, wv, acc0[c]);
      acc1[c] = fmaf(v1, wv, acc1[c]);
    }
  }
  float* op = out + (size_t)n * Cc * P + pbase;
  #pragma unroll
  for (int c = 0; c < CW; ++c)
    *reinterpret_cast<float2*>(op + (size_t)(co0 + c) * P) = make_float2(acc0[c], acc1[c]);
}

template<int CW>
__global__ __launch_bounds__(256) void conv1x1_k(const int* flag, void* dout, const void* in,
                                                 size_t w_off, size_t b_off,
                                                 size_t o_reg, size_t o_off, int P) {
  int f32 = __builtin_amdgcn_readfirstlane(*flag);
  const float* wt   = scrp(dout, f32, OFF_LR, w_off);
  const float* bias = scrp(dout, f32, OFF_LR, b_off);
  float* out        = scrp(dout, f32, o_reg, o_off);
  const int tid = threadIdx.x;
  const int n = blockIdx.z;
  const int pbase = (blockIdx.x * 64 + (tid & 63)) * 2;   // 128 px per block
  const int co0 = __builtin_amdgcn_readfirstlane(blockIdx.y * 4 * CW + (tid >> 6) * CW);
  if (f32) conv1x1_core<float, CW>((const float*)in, wt, bias, out, P, n, pbase, co0);
  else     conv1x1_core<bf16, CW>((const bf16*)in, wt, bias, out, P, n, pbase, co0);
}

// ---------------------------------------------------------------------------
// 3x3 conv body, pad=1 (f32 scratch in/out); register-staged prefetch.
// ---------------------------------------------------------------------------
constexpr int STG_TOT = 16 * 324;        // 5184 floats per chunk
constexpr int NSTG    = 21;              // ceil(5184/256) regs per thread

template<int KO, int KOG>
__device__ __forceinline__ void conv3x3_body(const float* __restrict__ in,
                                             const float* __restrict__ wt,
                                             const float* __restrict__ bias,
                                             float* __restrict__ out,
                                             int hh, int ww, int n, int ko0,
                                             int bx, int by, float* tile) {
  const int tid = threadIdx.x;
  const int tx = tid & 15, ty = tid >> 4;
  const bool inter = (bx >= 16) && (by >= 16) && (bx + 32 <= ww) && (by + 32 <= hh);

  float acc[KOG];
  #pragma unroll
  for (int ko = 0; ko < KOG; ++ko) acc[ko] = bias[ko0 + ko];

  float rg[NSTG];
  #pragma unroll
  for (int j = 0; j < NSTG; ++j) {
    int i = tid + j * 256;
    if (i < STG_TOT) {
      int ci = i / 324, r = i % 324, yy = r / 18, xx = r % 18;
      int gy = by + yy - 1, gx = bx + xx - 1;
      float v = 0.f;
      if (inter || (gy >= 0 && gy < hh && gx >= 0 && gx < ww))
        v = in[(((size_t)n * Cc + ci) * hh + gy) * ww + gx];
      rg[j] = v;
    }
  }

  for (int cc = 0; cc < Cc; cc += 16) {
    __syncthreads();
    #pragma unroll
    for (int j = 0; j < NSTG; ++j) {
      int i = tid + j * 256;
      if (i < STG_TOT) tile[i] = rg[j];
    }
    __syncthreads();
    if (cc + 16 < Cc) {
      #pragma unroll
      for (int j = 0; j < NSTG; ++j) {
        int i = tid + j * 256;
        if (i < STG_TOT) {
          int ci = i / 324, r = i % 324, yy = r / 18, xx = r % 18;
          int gy = by + yy - 1, gx = bx + xx - 1;
          float v = 0.f;
          if (inter || (gy >= 0 && gy < hh && gx >= 0 && gx < ww))
            v = in[(((size_t)n * Cc + cc + 16 + ci) * hh + gy) * ww + gx];
          rg[j] = v;
        }
      }
    }
    for (int ci = 0; ci < 16; ++ci) {
      float nb[9];
      #pragma unroll
      for (int dy = 0; dy < 3; ++dy)
        #pragma unroll
        for (int dx = 0; dx < 3; ++dx)
          nb[dy * 3 + dx] = tile[ci * 324 + (ty + dy) * 18 + tx + dx];
      const float* wr = wt + ((size_t)(cc + ci) * KO + ko0) * 9;
      #pragma unroll
      for (int ko = 0; ko < KOG; ++ko)
        #pragma unroll
        for (int k = 0; k < 9; ++k)
          acc[ko] = fmaf(wr[ko * 9 + k], nb[k], acc[ko]);
    }
  }
  const size_t ob = (((size_t)n * KO + ko0) * hh + by + ty) * ww + bx + tx;
  #pragma unroll
  for (int ko = 0; ko < KOG; ++ko) out[ob + (size_t)ko * hh * ww] = acc[ko];
}

template<int KO, int KOG>
__global__ __launch_bounds__(256) void conv3x3_k(const int* flag, void* dout,
                                                 size_t i_reg, size_t i_off,
                                                 size_t w_off, size_t b_off,
                                                 size_t o_reg, size_t o_off, int hh, int ww) {
  const int f32 = __builtin_amdgcn_readfirstlane(*flag);
  const float* in   = scrp(dout, f32, i_reg, i_off);
  const float* wt   = scrp(dout, f32, OFF_LR, w_off);
  const float* bias = scrp(dout, f32, OFF_LR, b_off);
  float* out        = scrp(dout, f32, o_reg, o_off);

  constexpr int NG = KO / KOG;
  __shared__ float tile[STG_TOT];
  const int n = blockIdx.z / NG;
  const int ko0 = (blockIdx.z % NG) * KOG;
  conv3x3_body<KO, KOG>(in, wt, bias, out, hh, ww, n, ko0, blockIdx.x * 16, blockIdx.y * 16, tile);
}

// D4: dual clf convs @64
__global__ __launch_bounds__(256) void conv3x3_dual_k(const int* flag, void* dout) {
  const int f32 = __builtin_amdgcn_readfirstlane(*flag);
  const float* clf   = scrp(dout, f32, OFF_HR, B_CLF);
  const float* wenc  = scrp(dout, f32, OFF_LR, A_WENC);
  const float* benc  = scrp(dout, f32, OFF_LR, A_BENC);
  const float* wenc2 = scrp(dout, f32, OFF_LR, A_WENC2);
  const float* benc2 = scrp(dout, f32, OFF_LR, A_BENC2);
  float* o_ll = scrp(dout, f32, OFF_LR, A_MLRLL);
  float* o_e2 = scrp(dout, f32, OFF_LR, A_CLFE2);
  __shared__ float tile[STG_TOT];
  const int z = blockIdx.z;
  const int g = z & 7, n = z >> 3;
  const int bx = blockIdx.x * 16, by = blockIdx.y * 16;
  if (g < 5) conv3x3_body<K2L, 5>(clf, wenc, benc, o_ll, Hl, Wl, n, g * 5, bx, by, tile);
  else       conv3x3_body<K2H, 3>(clf, wenc2, benc2, o_e2, Hl, Wl, n, (g - 5) * 3, bx, by, tile);
}

// ---------------------------------------------------------------------------
// s=1 CARAFE fused residual (scratch path, 1 px/thread) — unchanged.
// ---------------------------------------------------------------------------
template<typename FT, typename OT, int FINAL, int SM>
__device__ void carafe1_body(const FT* __restrict__ feat, const float* __restrict__ mask,
                             void* dout, size_t out_reg, float* outscr, int C, int CPB) {
  const int tid = threadIdx.x;
  const int tx = tid & 15, ty = tid >> 4;
  const int bx = blockIdx.x * 16, by = blockIdx.y * 16;
  const int numCG = C / CPB;
  const int n = blockIdx.z / numCG, cg = blockIdx.z % numCG;
  const int x = bx + tx, y = by + ty;
  const bool inter = (bx >= 16) && (by >= 16) && (bx + 32 <= Ww) && (by + 32 <= Hh);

  float mv[9];
  #pragma unroll
  for (int k = 0; k < 9; ++k)
    mv[k] = mask[(((size_t)n * 9 + k) * Hh + y) * Ww + x];
  if (SM) {
    float m = -1e30f;
    #pragma unroll
    for (int k = 0; k < 9; ++k) m = fmaxf(m, mv[k]);
    float s = 0.f;
    #pragma unroll
    for (int k = 0; k < 9; ++k) { mv[k] = __expf(mv[k] - m); s += mv[k]; }
    const float inv = 1.0f / s;
    #pragma unroll
    for (int k = 0; k < 9; ++k) mv[k] *= inv;
  }

  const int c0 = cg * CPB;
  if (inter) {
    for (int c = c0; c < c0 + CPB; ++c) {
      const FT* fp = feat + ((size_t)n * C + c) * HWh + (size_t)y * Ww + x;
      float center = tofloat(fp[0]);
      float s = 0.f;
      #pragma unroll
      for (int dy = -1; dy <= 1; ++dy)
        #pragma unroll
        for (int dx = -1; dx <= 1; ++dx)
          s = fmaf(tofloat(fp[dy * Ww + dx]), mv[(dy + 1) * 3 + (dx + 1)], s);
      float r = 2.f * center - s;
      const size_t li = ((size_t)n * C + c) * HWh + (size_t)y * Ww + x;
      if (FINAL) ((OT*)dout)[out_reg + li] = fromfloat<OT>(r);
      else       outscr[li] = r;
    }
  } else {
    for (int c = c0; c < c0 + CPB; ++c) {
      const FT* fp = feat + ((size_t)n * C + c) * HWh;
      float s = 0.f, center = 0.f;
      #pragma unroll
      for (int dy = -1; dy <= 1; ++dy)
        #pragma unroll
        for (int dx = -1; dx <= 1; ++dx) {
          int yy = y + dy, xx = x + dx;
          float fv = 0.f;
          if (yy >= 0 && yy < Hh && xx >= 0 && xx < Ww) fv = tofloat(fp[yy * Ww + xx]);
          if (dy == 0 && dx == 0) center = fv;
          s = fmaf(fv, mv[(dy + 1) * 3 + (dx + 1)], s);
        }
      float r = 2.f * center - s;
      const size_t li = ((size_t)n * C + c) * HWh + (size_t)y * Ww + x;
      if (FINAL) ((OT*)dout)[out_reg + li] = fromfloat<OT>(r);
      else       outscr[li] = r;
    }
  }
}

// D5: feat/mask f32 scratch, softmax fused, out scratch
__global__ __launch_bounds__(256) void carafe1_scr_k(const int* flag, void* dout,
    size_t f_reg, size_t f_off, size_t m_reg, size_t m_off, size_t o_reg, size_t o_off,
    int C, int CPB) {
  int f32 = __builtin_amdgcn_readfirstlane(*flag);
  carafe1_body<float, float, 0, 1>(scrp(dout, f32, f_reg, f_off), scrp(dout, f32, m_reg, m_off),
                                   dout, 0, scrp(dout, f32, o_reg, o_off), C, CPB);
}

// ---------------------------------------------------------------------------
// D9: final s=1 CARAFE, 2 adjacent px/thread, packed loads/stores.
// 32x16 px tile; x0 = bx + 2*tx (even). Softmax fused (raw f32 mask).
// ---------------------------------------------------------------------------
template<typename FT>
__device__ void carafe1_io2_body(const FT* __restrict__ feat, const float* __restrict__ mask,
                                 FT* __restrict__ outp, int C, int CPB) {
  const int tid = threadIdx.x;
  const int tx = tid & 15, ty = tid >> 4;
  const int bx = blockIdx.x * 32, by = blockIdx.y * 16;
  const int numCG = C / CPB;
  const int n = blockIdx.z / numCG, cg = blockIdx.z % numCG;
  const int x0 = bx + 2 * tx, y = by + ty;
  // interior: all reads rows y-1..y+1, cols x0-2..x0+3 in-bounds for every thread
  const bool inter = (bx >= 2) && (by >= 1) && (bx + 34 <= Ww) && (by + 17 <= Hh);

  float mv0[9], mv1[9];
  #pragma unroll
  for (int k = 0; k < 9; ++k) {
    float2 m2 = *reinterpret_cast<const float2*>(mask + (((size_t)n * 9 + k) * Hh + y) * Ww + x0);
    mv0[k] = m2.x; mv1[k] = m2.y;
  }
  {
    float m = -1e30f;
    #pragma unroll
    for (int k = 0; k < 9; ++k) m = fmaxf(m, mv0[k]);
    float s = 0.f;
    #pragma unroll
    for (int k = 0; k < 9; ++k) { mv0[k] = __expf(mv0[k] - m); s += mv0[k]; }
    const float inv = 1.0f / s;
    #pragma unroll
    for (int k = 0; k < 9; ++k) mv0[k] *= inv;
  }
  {
    float m = -1e30f;
    #pragma unroll
    for (int k = 0; k < 9; ++k) m = fmaxf(m, mv1[k]);
    float s = 0.f;
    #pragma unroll
    for (int k = 0; k < 9; ++k) { mv1[k] = __expf(mv1[k] - m); s += mv1[k]; }
    const float inv = 1.0f / s;
    #pragma unroll
    for (int k = 0; k < 9; ++k) mv1[k] *= inv;
  }

  const int c0 = cg * CPB;
  if (inter) {
    for (int c = c0; c < c0 + CPB; ++c) {
      const FT* fp = feat + ((size_t)n * C + c) * HWh;
      float s0 = 0.f, s1 = 0.f, c0v = 0.f, c1v = 0.f;
      #pragma unroll
      for (int dy = -1; dy <= 1; ++dy) {
        const FT* rp = fp + (size_t)(y + dy) * Ww + x0 - 2;   // cols x0-2 .. x0+3
        float v[6];
        if (sizeof(FT) == 2) {
          const unsigned* up = reinterpret_cast<const unsigned*>(rp);
          unsigned u0 = up[0], u1 = up[1], u2 = up[2];
          v[0] = __uint_as_float(u0 << 16); v[1] = __uint_as_float(u0 & 0xffff0000u);
          v[2] = __uint_as_float(u1 << 16); v[3] = __uint_as_float(u1 & 0xffff0000u);
          v[4] = __uint_as_float(u2 << 16); v[5] = __uint_as_float(u2 & 0xffff0000u);
        } else {
          const float2* qp = reinterpret_cast<const float2*>(rp);
          float2 a = qp[0], b = qp[1], cq = qp[2];
          v[0] = a.x; v[1] = a.y; v[2] = b.x; v[3] = b.y; v[4] = cq.x; v[5] = cq.y;
        }
        if (dy == 0) { c0v = v[2]; c1v = v[3]; }
        #pragma unroll
        for (int dx = 0; dx < 3; ++dx) {
          s0 = fmaf(v[1 + dx], mv0[(dy + 1) * 3 + dx], s0);
          s1 = fmaf(v[2 + dx], mv1[(dy + 1) * 3 + dx], s1);
        }
      }
      float r0 = 2.f * c0v - s0, r1 = 2.f * c1v - s1;
      const size_t li = ((size_t)n * C + c) * HWh + (size_t)y * Ww + x0;
      if (sizeof(FT) == 2) {
        bf16 b0 = __float2bfloat16(r0), b1 = __float2bfloat16(r1);
        *reinterpret_cast<unsigned*>(outp + li) =
            (unsigned)bfbits(b0) | ((unsigned)bfbits(b1) << 16);
      } else {
        *reinterpret_cast<float2*>(outp + li) = make_float2(r0, r1);
      }
    }
  } else {
    for (int c = c0; c < c0 + CPB; ++c) {
      const FT* fp = feat + ((size_t)n * C + c) * HWh;
      #pragma unroll
      for (int px = 0; px < 2; ++px) {
        const int x = x0 + px;
        float s = 0.f, center = 0.f;
        #pragma unroll
        for (int dy = -1; dy <= 1; ++dy)
          #pragma unroll
          for (int dx = -1; dx <= 1; ++dx) {
            int yy = y + dy, xx = x + dx;
            float fv = 0.f;
            if (yy >= 0 && yy < Hh && xx >= 0 && xx < Ww) fv = tofloat(fp[yy * Ww + xx]);
            if (dy == 0 && dx == 0) center = fv;
            float mw = px ? mv1[(dy + 1) * 3 + (dx + 1)] : mv0[(dy + 1) * 3 + (dx + 1)];
            s = fmaf(fv, mw, s);
          }
        float r = 2.f * center - s;
        outp[((size_t)n * C + c) * HWh + (size_t)y * Ww + x] = fromfloat<FT>(r);
      }
    }
  }
}

__global__ __launch_bounds__(256) void carafe1_io2_k(const int* flag, void* dout, const void* feat,
    size_t m_reg, size_t m_off, size_t out_reg, int C, int CPB) {
  int f32 = __builtin_amdgcn_readfirstlane(*flag);
  const float* m = scrp(dout, f32, m_reg, m_off);
  if (f32) carafe1_io2_body<float>((const float*)feat, m, (float*)dout + out_reg, C, CPB);
  else     carafe1_io2_body<bf16>((const bf16*)feat, m, (bf16*)dout + out_reg, C, CPB);
}

// ---------------------------------------------------------------------------
// s=2 CARAFE (scratch path, 1 px/thread) — unchanged.
// ---------------------------------------------------------------------------
template<typename FT, typename MT, typename OT, typename MOT, int ADD, int FINAL, int SM, int WMASK>
__device__ void carafe2_body(const FT* __restrict__ feat, const MT* __restrict__ mask,
                             const float* __restrict__ addend, void* dout, size_t out_reg,
                             float* outscr, int C, int CPB) {
  __shared__ float ft[8][144];
  const int tid = threadIdx.x;
  const int tx = tid & 15, ty = tid >> 4;
  const int bx = blockIdx.x * 16, by = blockIdx.y * 16;
  const int numCG = C / CPB;
  const int n = blockIdx.z / numCG, cg = blockIdx.z % numCG;
  const int x = bx + tx, y = by + ty;
  const bool inter = (bx >= 16) && (by >= 16) && (bx + 32 <= Ww) && (by + 32 <= Hh);

  float mv[25];
  #pragma unroll
  for (int k = 0; k < 25; ++k)
    mv[k] = tofloat(mask[(((size_t)n * 25 + k) * Hh + y) * Ww + x]);
  if (SM) {
    float m = -1e30f;
    #pragma unroll
    for (int k = 0; k < 25; ++k) m = fmaxf(m, mv[k]);
    float s = 0.f;
    #pragma unroll
    for (int k = 0; k < 25; ++k) { mv[k] = __expf(mv[k] - m); s += mv[k]; }
    const float inv = 1.0f / s;
    #pragma unroll
    for (int k = 0; k < 25; ++k) mv[k] *= inv;
  }
  if (WMASK && cg == 0) {
    const size_t g = (size_t)n * 25 * HWh + (size_t)y * Ww + x;
    MOT* mo = (MOT*)dout;
    #pragma unroll
    for (int k = 0; k < 25; ++k) mo[g + (size_t)k * HWh] = fromfloat<MOT>(mv[k]);
  }

  const int fy0 = (by >> 1) - 2, fx0 = (bx >> 1) - 2;
  const int fyb = (ty >> 1) + 2, fxb = (tx >> 1) + 2;
  const int c0 = cg * CPB;

  for (int cb = 0; cb < CPB; cb += 8) {
    const int lim = (CPB - cb < 8) ? (CPB - cb) : 8;
    __syncthreads();
    if (inter) {
      for (int i = tid; i < lim * 144; i += 256) {
        int cc = i / 144, r = i % 144, fy = r / 12, fx = r % 12;
        ft[cc][r] = tofloat(feat[((size_t)n * C + c0 + cb + cc) * HWl + (fy0 + fy) * Wl + fx0 + fx]);
      }
    } else {
      for (int i = tid; i < lim * 144; i += 256) {
        int cc = i / 144, r = i % 144, fy = r / 12, fx = r % 12;
        int gy = fy0 + fy, gx = fx0 + fx;
        float v = 0.f;
        if (gy >= 0 && gy < Hl && gx >= 0 && gx < Wl)
          v = tofloat(feat[((size_t)n * C + c0 + cb + cc) * HWl + gy * Wl + gx]);
        ft[cc][r] = v;
      }
    }
    __syncthreads();
    for (int cc = 0; cc < lim; ++cc) {
      float s = 0.f;
      #pragma unroll
      for (int ki = 0; ki < 5; ++ki)
        #pragma unroll
        for (int kj = 0; kj < 5; ++kj)
          s = fmaf(ft[cc][(fyb + ki - 2) * 12 + (fxb + kj - 2)], mv[ki * 5 + kj], s);
      const size_t li = (((size_t)n * C + c0 + cb + cc) * Hh + y) * Ww + x;
      float r = ADD ? (addend[li] + s) : s;
      if (FINAL) ((OT*)dout)[out_reg + li] = fromfloat<OT>(r);
      else       outscr[li] = r;
    }
  }
}

// D7: all f32 scratch, mask raw (softmax fused), ADD
__global__ __launch_bounds__(256) void carafe2_scr_k(const int* flag, void* dout,
    size_t f_reg, size_t f_off, size_t m_reg, size_t m_off, size_t a_reg, size_t a_off,
    size_t o_reg, size_t o_off, int C, int CPB) {
  int f32 = __builtin_amdgcn_readfirstlane(*flag);
  carafe2_body<float, float, float, float, 1, 0, 1, 0>(
      scrp(dout, f32, f_reg, f_off), scrp(dout, f32, m_reg, m_off),
      scrp(dout, f32, a_reg, a_off), dout, 0, scrp(dout, f32, o_reg, o_off), C, CPB);
}

// D8: mask_hr = mask_hr_hr + carafe_s2(clf_e2, softmax(mask_lr raw)); ALSO
// writes softmax(mask_lr) to final output 0.
__global__ __launch_bounds__(256) void carafe2_m0_k(const int* flag, void* dout,
    size_t f_reg, size_t f_off, size_t m_reg, size_t m_off, size_t a_reg, size_t a_off,
    size_t o_reg, size_t o_off, int C, int CPB) {
  int f32 = __builtin_amdgcn_readfirstlane(*flag);
  const float* f = scrp(dout, f32, f_reg, f_off);
  const float* m = scrp(dout, f32, m_reg, m_off);
  const float* a = scrp(dout, f32, a_reg, a_off);
  float* o = scrp(dout, f32, o_reg, o_off);
  if (f32) carafe2_body<float, float, float, float, 1, 0, 1, 1>(f, m, a, dout, 0, o, C, CPB);
  else     carafe2_body<float, float, float, bf16, 1, 0, 1, 1>(f, m, a, dout, 0, o, C, CPB);
}

// ---------------------------------------------------------------------------
// D10: final s=2 CARAFE, 2 adjacent px/thread. Adjacent px share the SAME
// source window (s=2) -> second pixel costs 25 FMA, zero extra LDS reads.
// 32x16 px tile -> ft[8][12*20]. Packed feat staging + packed mask/stores.
// ---------------------------------------------------------------------------
template<typename FT>
__device__ void carafe2_io2_body(const FT* __restrict__ feat, const FT* __restrict__ maskO,
                                 FT* __restrict__ outp, int C, int CPB) {
  __shared__ float ft[8][240];
  const int tid = threadIdx.x;
  const int tx = tid & 15, ty = tid >> 4;
  const int bx = blockIdx.x * 32, by = blockIdx.y * 16;
  const int numCG = C / CPB;
  const int n = blockIdx.z / numCG, cg = blockIdx.z % numCG;
  const int x0 = bx + 2 * tx, y = by + ty;

  float mv0[25], mv1[25];
  #pragma unroll
  for (int k = 0; k < 25; ++k) {
    const FT* mp = maskO + (((size_t)n * 25 + k) * Hh + y) * Ww + x0;
    if (sizeof(FT) == 2) {
      unsigned u = *reinterpret_cast<const unsigned*>(mp);
      mv0[k] = __uint_as_float(u << 16);
      mv1[k] = __uint_as_float(u & 0xffff0000u);
    } else {
      float2 m2 = *reinterpret_cast<const float2*>(mp);
      mv0[k] = m2.x; mv1[k] = m2.y;
    }
  }

  const int fy0 = (by >> 1) - 2, fx0 = (bx >> 1) - 2;
  const int fyb = (ty >> 1) + 2, fxc = tx + 2;   // both px share col fxc
  const int c0 = cg * CPB;
  const bool stg_ok = (fy0 >= 0) && (fy0 + 12 <= Hl) && (fx0 >= 0) && (fx0 + 20 <= Wl);

  for (int cb = 0; cb < CPB; cb += 8) {
    const int lim = (CPB - cb < 8) ? (CPB - cb) : 8;
    __syncthreads();
    if (stg_ok) {
      for (int i = tid; i < lim * 120; i += 256) {
        int cc = i / 120, r = i % 120, fy = r / 10, fx2 = (r % 10) * 2;
        const FT* sp = feat + ((size_t)n * C + c0 + cb + cc) * HWl + (size_t)(fy0 + fy) * Wl + fx0 + fx2;
        float a, b;
        if (sizeof(FT) == 2) {
          unsigned u = *reinterpret_cast<const unsigned*>(sp);
          a = __uint_as_float(u << 16);
          b = __uint_as_float(u & 0xffff0000u);
        } else {
          float2 f2 = *reinterpret_cast<const float2*>(sp);
          a = f2.x; b = f2.y;
        }
        ft[cc][fy * 20 + fx2]     = a;
        ft[cc][fy * 20 + fx2 + 1] = b;
      }
    } else {
      for (int i = tid; i < lim * 240; i += 256) {
        int cc = i / 240, r = i % 240, fy = r / 20, fx = r % 20;
        int gy = fy0 + fy, gx = fx0 + fx;
        float v = 0.f;
        if (gy >= 0 && gy < Hl && gx >= 0 && gx < Wl)
          v = tofloat(feat[((size_t)n * C + c0 + cb + cc) * HWl + (size_t)gy * Wl + gx]);
        ft[cc][r] = v;
      }
    }
    __syncthreads();
    for (int cc = 0; cc < lim; ++cc) {
      float s0 = 0.f, s1 = 0.f;
      #pragma unroll
      for (int ki = 0; ki < 5; ++ki)
        #pragma unroll
        for (int kj = 0; kj < 5; ++kj) {
          float fv = ft[cc][(fyb + ki - 2) * 20 + (fxc + kj - 2)];
          s0 = fmaf(fv, mv0[ki * 5 + kj], s0);
          s1 = fmaf(fv, mv1[ki * 5 + kj], s1);
        }
      const size_t li = (((size_t)n * C + c0 + cb + cc) * Hh + y) * Ww + x0;
      if (sizeof(FT) == 2) {
        bf16 b0 = __float2bfloat16(s0), b1 = __float2bfloat16(s1);
        *reinterpret_cast<unsigned*>(outp + li) =
            (unsigned)bfbits(b0) | ((unsigned)bfbits(b1) << 16);
      } else {
        *reinterpret_cast<float2*>(outp + li) = make_float2(s0, s1);
      }
    }
  }
}

__global__ __launch_bounds__(256) void carafe2_io2_k(const int* flag, void* dout, const void* feat,
    size_t out_reg, int C, int CPB) {
  int f32 = __builtin_amdgcn_readfirstlane(*flag);
  if (f32) carafe2_io2_body<float>((const float*)feat, (const float*)dout, (float*)dout + out_reg, C, CPB);
  else     carafe2_io2_body<bf16>((const bf16*)feat, (const bf16*)dout, (bf16*)dout + out_reg, C, CPB);
}

// ---------------------------------------------------------------------------
extern "C" void kernel_launch(void* const* d_in, const int* in_sizes, int n_in,
                              void* d_out, int out_size, void* d_ws, size_t ws_size,
                              hipStream_t stream) {
  const void* hr_feat = d_in[0];
  const void* lr_feat = d_in[1];
  int* flag = (int*)d_ws;  // only 4 bytes of ws used

  // D0. dtype detect
  detect_dtype<<<1, 256, 0, stream>>>(hr_feat, flag);
  // D1. weight prep -> arena A weight slots
  prep_weights<<<64, 256, 0, stream>>>(flag, d_out, d_in[2], d_in[3], d_in[4], d_in[5],
                                       d_in[6], d_in[7], d_in[8], d_in[9]);
  // D2. chf = conv1x1(hr_feat) -> A   (CW=8, 2-px packed, 1024 blocks)
  conv1x1_k<8><<<dim3(HWh / 128, 2, Nn), 256, 0, stream>>>(flag, d_out, hr_feat, A_WHR, A_BHR, OFF_LR, A_CHF, HWh);
  // D3a. clf = conv1x1(lr_feat) -> B  (CW=4, 512 blocks)
  conv1x1_k<4><<<dim3(HWl / 128, 4, Nn), 256, 0, stream>>>(flag, d_out, lr_feat, A_WLR, A_BLR, OFF_HR, B_CLF, HWl);
  // D3b. mask_hr_hr = conv3x3(chf, enc2) -> B  (KO=9 split x3, 768 blocks)
  conv3x3_k<K2H, 3><<<dim3(8, 8, Nn * 3), 256, 0, stream>>>(flag, d_out, OFF_LR, A_CHF, A_WENC2, A_BENC2, OFF_HR, B_MHRHR, Hh, Ww);
  // D4. {m_lr_ll, clf_e2} = conv3x3(clf, enc/enc2) -> A  (512 blocks)
  conv3x3_dual_k<<<dim3(4, 4, Nn * 8), 256, 0, stream>>>(flag, d_out);
  // D5. chf2 = 2*chf - carafe_s1(chf, softmax(mask_hr_hr)) -> B
  carafe1_scr_k<<<dim3(8, 8, Nn * (Cc / 16)), 256, 0, stream>>>(flag, d_out, OFF_LR, A_CHF, OFF_HR, B_MHRHR, OFF_HR, B_CHF2, Cc, 16);
  // D6. mask_lr_hr = conv3x3(chf2, enc) -> A (chf dead)  (KO=25 split x5, 1280 blocks)
  conv3x3_k<K2L, 5><<<dim3(8, 8, Nn * 5), 256, 0, stream>>>(flag, d_out, OFF_HR, B_CHF2, A_WENC, A_BENC, OFF_LR, A_MLRHR, Hh, Ww);
  // D7. mask_lr = mask_lr_hr + carafe_s2(m_lr_ll, softmax(mask_lr_hr)) -> B
  carafe2_scr_k<<<dim3(8, 8, Nn * 5), 256, 0, stream>>>(flag, d_out, OFF_LR, A_MLRLL, OFF_LR, A_MLRHR,
                                                        OFF_LR, A_MLRHR, OFF_HR, B_MLR, K2L, 5);
  // D8. mask_hr(raw) = mask_hr_hr + carafe_s2(clf_e2, softmax(mask_lr)) -> A
  //     + write softmax(mask_lr) -> FINAL output 0
  carafe2_m0_k<<<dim3(8, 8, Nn * 3), 256, 0, stream>>>(flag, d_out, OFF_LR, A_CLFE2,
                                                       OFF_HR, B_MLR, OFF_HR, B_MHRHR,
                                                       OFF_LR, A_MHRRAW, K2H, 3);
  // D9. hr_out = 2*hr_feat - carafe_s1(hr_feat, softmax(mask_hr)) -> FINAL out_hr
  //     (2-px/thread packed, 2048 blocks)
  carafe1_io2_k<<<dim3(Ww / 32, Hh / 16, Nn * (Ci / 16)), 256, 0, stream>>>(flag, d_out, hr_feat,
                                                                            OFF_LR, A_MHRRAW, OFF_HR, Ci, 16);
  // D10 (last). lr_out = carafe_s2(lr_feat, mask_lr_out) -> FINAL out_lr
  //     (2-px/thread shared-window, 2048 blocks; overwrites arena A)
  carafe2_io2_k<<<dim3(Ww / 32, Hh / 16, Nn * (Ci / 16)), 256, 0, stream>>>(flag, d_out, lr_feat, OFF_LR, Ci, 16);
}